// Round 5
// baseline (59.428 us; speedup 1.0000x reference)
//
#include <hip/hip_runtime.h>

#define BATCH 32
#define LATENT 128
#define NODE_DIM 8
#define MAX_NODES 512
#define H_NODE 128
#define H_EDGE 64

typedef float f32x2 __attribute__((ext_vector_type(2)));

// ws layout: UPK[32][32][512][2] (4MB) | V[32][512][64] (4MB)
#define UPK_ELEMS (BATCH * 32 * MAX_NODES * 2)

// ---------------------------------------------------------------------------
// Kernel 1 (UNCHANGED from R3/R4): nodes + U/V precompute.
// ---------------------------------------------------------------------------
__global__ __launch_bounds__(256) void gen_nodes_uv(
    const float* __restrict__ z,  const float* __restrict__ W1,
    const float* __restrict__ b1, const float* __restrict__ W2,
    const float* __restrict__ b2, const float* __restrict__ E1,
    const float* __restrict__ eb1,
    float* __restrict__ nodes_out, float* __restrict__ UPK,
    float* __restrict__ Vws)
{
    const int b      = blockIdx.x;
    const int mslice = blockIdx.y;     // 0..15, 256 cols each
    const int tid    = threadIdx.x;    // 0..255
    const int i0     = mslice * 32;    // first node owned by this block

    __shared__ float sz[LATENT];
    __shared__ float sh[H_NODE];
    __shared__ float sE1[2 * NODE_DIM][H_EDGE];
    __shared__ float sEb1[H_EDGE];
    __shared__ float sN[32][NODE_DIM];

    if (tid < LATENT) sz[tid] = z[b * LATENT + tid];
    for (int idx = tid; idx < 2 * NODE_DIM * H_EDGE; idx += 256)
        (&sE1[0][0])[idx] = E1[idx];
    if (tid < H_EDGE) sEb1[tid] = eb1[tid];
    __syncthreads();

    if (tid < H_NODE) {
        float acc = b1[tid];
#pragma unroll 8
        for (int k = 0; k < LATENT; ++k)
            acc += sz[k] * W1[k * H_NODE + tid];
        sh[tid] = fmaxf(acc, 0.0f);
    }
    __syncthreads();

    const int m = mslice * 256 + tid;
    float acc = b2[m];
#pragma unroll 8
    for (int k = 0; k < H_NODE; ++k)
        acc += sh[k] * W2[(size_t)k * (MAX_NODES * NODE_DIM) + m];
    nodes_out[(size_t)b * (MAX_NODES * NODE_DIM) + m] = acc;
    sN[tid >> 3][tid & 7] = acc;
    __syncthreads();

    {
        const int il = tid & 31;
        const int cg = tid >> 5;
#pragma unroll
        for (int rep = 0; rep < 4; ++rep) {
            const int c2 = rep * 8 + cg;
            const int c  = 2 * c2;
            float ua = sEb1[c], ub = sEb1[c + 1];
#pragma unroll
            for (int d = 0; d < NODE_DIM; ++d) {
                const float nd = sN[il][d];
                ua += nd * sE1[d][c];
                ub += nd * sE1[d][c + 1];
            }
            f32x2 uu = {ua, ub};
            *(f32x2*)&UPK[(((size_t)b * 32 + c2) * MAX_NODES + i0 + il) * 2] = uu;
        }
    }
    {
        const int jl = tid >> 3;
        const int cq = tid & 7;
#pragma unroll
        for (int rep = 0; rep < 4; ++rep) {
            const int c2 = rep * 8 + cq;
            const int c  = 2 * c2;
            float va = 0.f, vb = 0.f;
#pragma unroll
            for (int d = 0; d < NODE_DIM; ++d) {
                const float nd = sN[jl][d];
                va += nd * sE1[NODE_DIM + d][c];
                vb += nd * sE1[NODE_DIM + d][c + 1];
            }
            f32x2 vv = {va, vb};
            *(f32x2*)&Vws[((size_t)(b * MAX_NODES + i0 + jl) << 6) + c] = vv;
        }
    }
}

// ---------------------------------------------------------------------------
// Kernel 2: edge probabilities + adjacency.
// Block = 256 thr (4 waves), tile 128 i x 32 j. Lane owns i and i+64 (U rows
// register-resident, 128 VGPR); wave w owns 8 j. V tile in LDS read as
// ds_read_b128 (4 ch/read) -> 16 LDS reads per jj vs 256 VALU: VALU-bound.
// 40 tiles/batch (jt >= 4*bi). E2 -> SGPRs (uniform).
// ---------------------------------------------------------------------------
__global__ __launch_bounds__(256) void edge_gen(
    const float* __restrict__ UPK, const float* __restrict__ Vws,
    const float* __restrict__ E2,  const float* __restrict__ eb2,
    float* __restrict__ adj)
{
    const int b = blockIdx.y;
    // decode tile: bi in 0..3 (128-wide i), jt in 4*bi..15 (32-wide j)
    int t = blockIdx.x, bi = 0;
    while (t >= 16 - 4 * bi) { t -= 16 - 4 * bi; ++bi; }
    const int jt = 4 * bi + t;
    const bool partial = (jt >> 2) == bi;    // j-window inside i-block

    const int tid  = threadIdx.x;
    const int lane = tid & 63;
    const int wv   = tid >> 6;               // 0..3
    const int i0 = bi * 128, j0 = jt * 32;
    const int iA = i0 + lane, iB = iA + 64;

    __shared__ float sV[32][H_EDGE];         // V rows for the j-tile (8 KB)
    __shared__ float P[32][129];             // tile probs for mirror (16.5 KB)

    // stage V tile: 8 KB contiguous
    {
        const float4* src = (const float4*)(Vws + ((size_t)(b * MAX_NODES + j0) << 6));
        float4* dst = (float4*)&sV[0][0];
        dst[tid]       = src[tid];
        dst[tid + 256] = src[tid + 256];
    }

    // U rows for both i's: 32 packed pairs each, coalesced per c2
    f32x2 uA[32], uB[32];
#pragma unroll
    for (int c2 = 0; c2 < 32; ++c2) {
        const float* base = &UPK[((size_t)b * 32 + c2) * MAX_NODES * 2];
        uA[c2] = *(const f32x2*)(base + 2 * iA);
        uB[c2] = *(const f32x2*)(base + 2 * iB);
    }

    const f32x2* w2 = (const f32x2*)E2;
    const float bias = eb2[0];
    const f32x2 z2 = {0.f, 0.f};
    float* adjb = adj + (size_t)b * MAX_NODES * MAX_NODES;
    __syncthreads();

#pragma unroll 1
    for (int jj = 0; jj < 8; ++jj) {
        const int jl = wv * 8 + jj;          // 0..31
        const int j  = j0 + jl;
        const float4* vrow = (const float4*)&sV[jl][0];

        f32x2 aA0 = z2, aA1 = z2, aB0 = z2, aB1 = z2;
#pragma unroll
        for (int q = 0; q < 16; ++q) {
            const float4 vv = vrow[q];       // ds_read_b128, uniform
            const f32x2 v0 = {vv.x, vv.y}, v1 = {vv.z, vv.w};
            const f32x2 w0 = w2[2 * q], w1 = w2[2 * q + 1];
            f32x2 s;
            s = uA[2 * q]     + v0; s = __builtin_elementwise_max(s, z2); aA0 += w0 * s;
            s = uA[2 * q + 1] + v1; s = __builtin_elementwise_max(s, z2); aA1 += w1 * s;
            s = uB[2 * q]     + v0; s = __builtin_elementwise_max(s, z2); aB0 += w0 * s;
            s = uB[2 * q + 1] + v1; s = __builtin_elementwise_max(s, z2); aB1 += w1 * s;
        }
        const float xA = aA0.x + aA0.y + aA1.x + aA1.y + bias;
        const float xB = aB0.x + aB0.y + aB1.x + aB1.y + bias;
        const float pA = 1.0f / (1.0f + __expf(-xA));
        const float pB = 1.0f / (1.0f + __expf(-xB));

        if (!partial) {
            adjb[(size_t)j * MAX_NODES + iA] = pA;   // lower half, coalesced
            adjb[(size_t)j * MAX_NODES + iB] = pB;
            P[jl][lane]      = pA;                   // stage for mirror
            P[jl][64 + lane] = pB;
        } else {
            if (iA < j)       { adjb[(size_t)j * MAX_NODES + iA] = pA;
                                adjb[(size_t)iA * MAX_NODES + j] = pA; }
            else if (iA == j)   adjb[(size_t)j * MAX_NODES + iA] = 0.0f;
            if (iB < j)       { adjb[(size_t)j * MAX_NODES + iB] = pB;
                                adjb[(size_t)iB * MAX_NODES + j] = pB; }
            else if (iB == j)   adjb[(size_t)j * MAX_NODES + iB] = 0.0f;
        }
    }

    if (!partial) {
        __syncthreads();
        // mirror: adj[i0+r][j0..j0+31]; thread owns row r = tid&127, half h
        const int r = tid & 127;
        const int h = tid >> 7;              // 0..1
        const size_t rowbase = (size_t)(i0 + r) * MAX_NODES + j0 + h * 16;
#pragma unroll
        for (int g = 0; g < 4; ++g) {
            const int c0 = h * 16 + 4 * g;
            float4 o;
            o.x = P[c0 + 0][r]; o.y = P[c0 + 1][r];
            o.z = P[c0 + 2][r]; o.w = P[c0 + 3][r];
            *(float4*)&adjb[rowbase + 4 * g] = o;    // 64B/line per thread
        }
    }
}

// ---------------------------------------------------------------------------
extern "C" void kernel_launch(void* const* d_in, const int* in_sizes, int n_in,
                              void* d_out, int out_size, void* d_ws, size_t ws_size,
                              hipStream_t stream)
{
    const float* z   = (const float*)d_in[0];
    const float* W1  = (const float*)d_in[1];
    const float* b1  = (const float*)d_in[2];
    const float* W2  = (const float*)d_in[3];
    const float* b2  = (const float*)d_in[4];
    const float* E1  = (const float*)d_in[5];
    const float* eb1 = (const float*)d_in[6];
    const float* E2  = (const float*)d_in[7];
    const float* eb2 = (const float*)d_in[8];

    float* nodes_out = (float*)d_out;                                   // [32,512,8]
    float* adj       = (float*)d_out + BATCH * MAX_NODES * NODE_DIM;    // [32,512,512]

    float* UPK = (float*)d_ws;                 // 4 MB
    float* Vws = UPK + UPK_ELEMS;              // 4 MB

    dim3 g1(BATCH, 16);
    gen_nodes_uv<<<g1, 256, 0, stream>>>(z, W1, b1, W2, b2, E1, eb1,
                                         nodes_out, UPK, Vws);

    dim3 g2(40, BATCH);
    edge_gen<<<g2, 256, 0, stream>>>(UPK, Vws, E2, eb2, adj);
}

// Round 6
// 48.715 us; speedup vs baseline: 1.2199x; 1.2199x over previous
//
#include <hip/hip_runtime.h>

#define BATCH 32
#define LATENT 128
#define NODE_DIM 8
#define MAX_NODES 512
#define H_NODE 128
#define H_EDGE 64

typedef _Float16 h2 __attribute__((ext_vector_type(2)));

static __device__ __forceinline__ h2 u32_to_h2(unsigned int x) {
    union { unsigned int u; h2 h; } c; c.u = x; return c.h;
}
static __device__ __forceinline__ unsigned int h2_to_u32(h2 x) {
    union { unsigned int u; h2 h; } c; c.h = x; return c.u;
}

#if __has_builtin(__builtin_amdgcn_fdot2)
#define FDOT2(a, b, c) __builtin_amdgcn_fdot2((a), (b), (c), false)
#else
#define FDOT2(a, b, c) ((c) + (float)(a).x * (float)(b).x + (float)(a).y * (float)(b).y)
#endif

// ws layout: UPKH u32[32][32][512] (2MB) | VH u32[32][512][32] (2MB)
#define UPKH_DWORDS (BATCH * 32 * MAX_NODES)

// ---------------------------------------------------------------------------
// Kernel 1: nodes (f32, d_out) + U/V precompute in packed f16.
//   UPKH[b][c2][i]  = f16x2(U[i][2c2], U[i][2c2+1])   (coalesced per-lane loads)
//   VH[b][j][c2]    = f16x2(V[j][2c2], V[j][2c2+1])   (128B rows for LDS stage)
// ---------------------------------------------------------------------------
__global__ __launch_bounds__(256) void gen_nodes_uv(
    const float* __restrict__ z,  const float* __restrict__ W1,
    const float* __restrict__ b1, const float* __restrict__ W2,
    const float* __restrict__ b2, const float* __restrict__ E1,
    const float* __restrict__ eb1,
    float* __restrict__ nodes_out, unsigned int* __restrict__ UPKH,
    unsigned int* __restrict__ VH)
{
    const int b      = blockIdx.x;
    const int mslice = blockIdx.y;     // 0..15, 256 cols each
    const int tid    = threadIdx.x;    // 0..255
    const int i0     = mslice * 32;    // first node owned by this block

    __shared__ float sz[LATENT];
    __shared__ float sh[H_NODE];
    __shared__ float sE1[2 * NODE_DIM][H_EDGE];
    __shared__ float sEb1[H_EDGE];
    __shared__ float sN[32][NODE_DIM];

    if (tid < LATENT) sz[tid] = z[b * LATENT + tid];
    for (int idx = tid; idx < 2 * NODE_DIM * H_EDGE; idx += 256)
        (&sE1[0][0])[idx] = E1[idx];
    if (tid < H_EDGE) sEb1[tid] = eb1[tid];
    __syncthreads();

    if (tid < H_NODE) {
        float acc = b1[tid];
#pragma unroll 8
        for (int k = 0; k < LATENT; ++k)
            acc += sz[k] * W1[k * H_NODE + tid];
        sh[tid] = fmaxf(acc, 0.0f);
    }
    __syncthreads();

    const int m = mslice * 256 + tid;
    float acc = b2[m];
#pragma unroll 8
    for (int k = 0; k < H_NODE; ++k)
        acc += sh[k] * W2[(size_t)k * (MAX_NODES * NODE_DIM) + m];
    nodes_out[(size_t)b * (MAX_NODES * NODE_DIM) + m] = acc;
    sN[tid >> 3][tid & 7] = acc;
    __syncthreads();

    {   // U' -> f16x2, layout [b][c2][i]
        const int il = tid & 31;
        const int cg = tid >> 5;
#pragma unroll
        for (int rep = 0; rep < 4; ++rep) {
            const int c2 = rep * 8 + cg;
            const int c  = 2 * c2;
            float ua = sEb1[c], ub = sEb1[c + 1];
#pragma unroll
            for (int d = 0; d < NODE_DIM; ++d) {
                const float nd = sN[il][d];
                ua += nd * sE1[d][c];
                ub += nd * sE1[d][c + 1];
            }
            h2 uu = { (_Float16)ua, (_Float16)ub };
            UPKH[((size_t)b * 32 + c2) * MAX_NODES + i0 + il] = h2_to_u32(uu);
        }
    }
    {   // V' -> f16x2, layout [b][j][c2] (128B rows)
        const int jl = tid >> 3;
        const int cq = tid & 7;
#pragma unroll
        for (int rep = 0; rep < 4; ++rep) {
            const int c2 = rep * 8 + cq;
            const int c  = 2 * c2;
            float va = 0.f, vb = 0.f;
#pragma unroll
            for (int d = 0; d < NODE_DIM; ++d) {
                const float nd = sN[jl][d];
                va += nd * sE1[NODE_DIM + d][c];
                vb += nd * sE1[NODE_DIM + d][c + 1];
            }
            h2 vv = { (_Float16)va, (_Float16)vb };
            VH[((size_t)(b * MAX_NODES + i0 + jl) << 5) + c2] = h2_to_u32(vv);
        }
    }
}

// ---------------------------------------------------------------------------
// Kernel 2: edge probabilities + adjacency.  (R5 geometry, f16 math)
// Block = 256 thr (4 waves), tile 128 i x 32 j. Lane owns iA=i0+lane and
// iB=iA+64; U rows in 64 VGPR (f16x2). V tile (4KB) in LDS, read as b128
// broadcast (8/jj). Inner math: v_pk_add_f16 + v_pk_max_f16 + v_dot2_f32_f16
// = 3 instr / 2 channels. E2 packed f16x2 in SGPRs via readfirstlane.
// 40 tiles/batch (jt >= 4*bi); partial iff jt>>2 == bi.
// ---------------------------------------------------------------------------
__global__ __launch_bounds__(256, 4) void edge_gen(
    const unsigned int* __restrict__ UPKH, const unsigned int* __restrict__ VH,
    const float* __restrict__ E2,  const float* __restrict__ eb2,
    float* __restrict__ adj)
{
    const int b = blockIdx.y;
    int t = blockIdx.x, bi = 0;
    while (t >= 16 - 4 * bi) { t -= 16 - 4 * bi; ++bi; }
    const int jt = 4 * bi + t;
    const bool partial = (jt >> 2) == bi;    // j-window inside i-block

    const int tid  = threadIdx.x;
    const int lane = tid & 63;
    const int wv   = tid >> 6;               // 0..3
    const int i0 = bi * 128, j0 = jt * 32;
    const int iA = i0 + lane, iB = iA + 64;

    __shared__ unsigned int sV[32 * 32];     // 32 rows x 64ch f16 = 4 KB
    __shared__ float P[32][129];             // tile probs for mirror (16.5 KB)

    // stage V tile: 4 KB contiguous, 1 float4 per thread
    {
        const float4* src = (const float4*)(VH + ((size_t)(b * MAX_NODES + j0) << 5));
        ((float4*)sV)[tid] = src[tid];
    }

    // U rows for both i's: 32 f16x2 dwords each, coalesced per c2
    unsigned int uA[32], uB[32];
#pragma unroll
    for (int c2 = 0; c2 < 32; ++c2) {
        const unsigned int* base = &UPKH[((size_t)b * 32 + c2) * MAX_NODES];
        uA[c2] = base[iA];
        uB[c2] = base[iB];
    }

    // E2 -> packed f16x2 in SGPRs
    unsigned int wb[32];
#pragma unroll
    for (int c2 = 0; c2 < 32; ++c2) {
        h2 w = { (_Float16)E2[2 * c2], (_Float16)E2[2 * c2 + 1] };
        wb[c2] = __builtin_amdgcn_readfirstlane(h2_to_u32(w));
    }

    const float bias = eb2[0];
    float* adjb = adj + (size_t)b * MAX_NODES * MAX_NODES;
    const h2 zh = { (_Float16)0.f, (_Float16)0.f };
    __syncthreads();

#pragma unroll 1
    for (int jj = 0; jj < 8; ++jj) {
        const int jl = wv * 8 + jj;          // 0..31
        const int j  = j0 + jl;
        const float4* vrow = (const float4*)&sV[jl * 32];

        float aA0 = 0.f, aA1 = 0.f, aB0 = 0.f, aB1 = 0.f;
#pragma unroll
        for (int q = 0; q < 8; ++q) {
            union { float4 f4; unsigned int u[4]; } vv;
            vv.f4 = vrow[q];                 // ds_read_b128, uniform
#pragma unroll
            for (int k = 0; k < 4; ++k) {
                const int c2 = 4 * q + k;
                const h2 v = u32_to_h2(vv.u[k]);
                const h2 w = u32_to_h2(wb[c2]);
                h2 sA = u32_to_h2(uA[c2]) + v;
                h2 sB = u32_to_h2(uB[c2]) + v;
                sA = __builtin_elementwise_max(sA, zh);
                sB = __builtin_elementwise_max(sB, zh);
                if (k & 1) { aA1 = FDOT2(sA, w, aA1); aB1 = FDOT2(sB, w, aB1); }
                else       { aA0 = FDOT2(sA, w, aA0); aB0 = FDOT2(sB, w, aB0); }
            }
        }
        const float xA = aA0 + aA1 + bias;
        const float xB = aB0 + aB1 + bias;
        const float pA = 1.0f / (1.0f + __expf(-xA));
        const float pB = 1.0f / (1.0f + __expf(-xB));

        if (!partial) {
            adjb[(size_t)j * MAX_NODES + iA] = pA;   // lower half, coalesced
            adjb[(size_t)j * MAX_NODES + iB] = pB;
            P[jl][lane]      = pA;                   // stage for mirror
            P[jl][64 + lane] = pB;
        } else {
            if (iA < j)       { adjb[(size_t)j * MAX_NODES + iA] = pA;
                                adjb[(size_t)iA * MAX_NODES + j] = pA; }
            else if (iA == j)   adjb[(size_t)j * MAX_NODES + iA] = 0.0f;
            if (iB < j)       { adjb[(size_t)j * MAX_NODES + iB] = pB;
                                adjb[(size_t)iB * MAX_NODES + j] = pB; }
            else if (iB == j)   adjb[(size_t)j * MAX_NODES + iB] = 0.0f;
        }
    }

    if (!partial) {
        __syncthreads();
        // mirror: adj[i0+r][j0..j0+31]; thread owns row r = tid&127, half h
        const int r = tid & 127;
        const int h = tid >> 7;              // 0..1
        const size_t rowbase = (size_t)(i0 + r) * MAX_NODES + j0 + h * 16;
#pragma unroll
        for (int g = 0; g < 4; ++g) {
            const int c0 = h * 16 + 4 * g;
            float4 o;
            o.x = P[c0 + 0][r]; o.y = P[c0 + 1][r];
            o.z = P[c0 + 2][r]; o.w = P[c0 + 3][r];
            *(float4*)&adjb[rowbase + 4 * g] = o;
        }
    }
}

// ---------------------------------------------------------------------------
extern "C" void kernel_launch(void* const* d_in, const int* in_sizes, int n_in,
                              void* d_out, int out_size, void* d_ws, size_t ws_size,
                              hipStream_t stream)
{
    const float* z   = (const float*)d_in[0];
    const float* W1  = (const float*)d_in[1];
    const float* b1  = (const float*)d_in[2];
    const float* W2  = (const float*)d_in[3];
    const float* b2  = (const float*)d_in[4];
    const float* E1  = (const float*)d_in[5];
    const float* eb1 = (const float*)d_in[6];
    const float* E2  = (const float*)d_in[7];
    const float* eb2 = (const float*)d_in[8];

    float* nodes_out = (float*)d_out;                                   // [32,512,8]
    float* adj       = (float*)d_out + BATCH * MAX_NODES * NODE_DIM;    // [32,512,512]

    unsigned int* UPKH = (unsigned int*)d_ws;       // 2 MB
    unsigned int* VHp  = UPKH + UPKH_DWORDS;        // 2 MB

    dim3 g1(BATCH, 16);
    gen_nodes_uv<<<g1, 256, 0, stream>>>(z, W1, b1, W2, b2, E1, eb1,
                                         nodes_out, UPKH, VHp);

    dim3 g2(40, BATCH);
    edge_gen<<<g2, 256, 0, stream>>>(UPKH, VHp, E2, eb2, adj);
}

// Round 7
// 45.876 us; speedup vs baseline: 1.2954x; 1.0619x over previous
//
#include <hip/hip_runtime.h>

#define BATCH 32
#define LATENT 128
#define NODE_DIM 8
#define MAX_NODES 512
#define H_NODE 128
#define H_EDGE 64

typedef _Float16 h2 __attribute__((ext_vector_type(2)));

static __device__ __forceinline__ h2 u32_to_h2(unsigned int x) {
    union { unsigned int u; h2 h; } c; c.u = x; return c.h;
}
static __device__ __forceinline__ unsigned int h2_to_u32(h2 x) {
    union { unsigned int u; h2 h; } c; c.h = x; return c.u;
}

#if __has_builtin(__builtin_amdgcn_fdot2)
#define FDOT2(a, b, c) __builtin_amdgcn_fdot2((a), (b), (c), false)
#else
#define FDOT2(a, b, c) ((c) + (float)(a).x * (float)(b).x + (float)(a).y * (float)(b).y)
#endif

// ws layout: UPKH u32[32][32][512] (2MB) | VH u32[32][512][32] (2MB)
#define UPKH_DWORDS (BATCH * 32 * MAX_NODES)

// ---------------------------------------------------------------------------
// Kernel 1 (UNCHANGED from R6): nodes (f32) + U/V precompute in packed f16.
// ---------------------------------------------------------------------------
__global__ __launch_bounds__(256) void gen_nodes_uv(
    const float* __restrict__ z,  const float* __restrict__ W1,
    const float* __restrict__ b1, const float* __restrict__ W2,
    const float* __restrict__ b2, const float* __restrict__ E1,
    const float* __restrict__ eb1,
    float* __restrict__ nodes_out, unsigned int* __restrict__ UPKH,
    unsigned int* __restrict__ VH)
{
    const int b      = blockIdx.x;
    const int mslice = blockIdx.y;     // 0..15, 256 cols each
    const int tid    = threadIdx.x;    // 0..255
    const int i0     = mslice * 32;    // first node owned by this block

    __shared__ float sz[LATENT];
    __shared__ float sh[H_NODE];
    __shared__ float sE1[2 * NODE_DIM][H_EDGE];
    __shared__ float sEb1[H_EDGE];
    __shared__ float sN[32][NODE_DIM];

    if (tid < LATENT) sz[tid] = z[b * LATENT + tid];
    for (int idx = tid; idx < 2 * NODE_DIM * H_EDGE; idx += 256)
        (&sE1[0][0])[idx] = E1[idx];
    if (tid < H_EDGE) sEb1[tid] = eb1[tid];
    __syncthreads();

    if (tid < H_NODE) {
        float acc = b1[tid];
#pragma unroll 8
        for (int k = 0; k < LATENT; ++k)
            acc += sz[k] * W1[k * H_NODE + tid];
        sh[tid] = fmaxf(acc, 0.0f);
    }
    __syncthreads();

    const int m = mslice * 256 + tid;
    float acc = b2[m];
#pragma unroll 8
    for (int k = 0; k < H_NODE; ++k)
        acc += sh[k] * W2[(size_t)k * (MAX_NODES * NODE_DIM) + m];
    nodes_out[(size_t)b * (MAX_NODES * NODE_DIM) + m] = acc;
    sN[tid >> 3][tid & 7] = acc;
    __syncthreads();

    {   // U' -> f16x2, layout [b][c2][i]
        const int il = tid & 31;
        const int cg = tid >> 5;
#pragma unroll
        for (int rep = 0; rep < 4; ++rep) {
            const int c2 = rep * 8 + cg;
            const int c  = 2 * c2;
            float ua = sEb1[c], ub = sEb1[c + 1];
#pragma unroll
            for (int d = 0; d < NODE_DIM; ++d) {
                const float nd = sN[il][d];
                ua += nd * sE1[d][c];
                ub += nd * sE1[d][c + 1];
            }
            h2 uu = { (_Float16)ua, (_Float16)ub };
            UPKH[((size_t)b * 32 + c2) * MAX_NODES + i0 + il] = h2_to_u32(uu);
        }
    }
    {   // V' -> f16x2, layout [b][j][c2] (128B rows)
        const int jl = tid >> 3;
        const int cq = tid & 7;
#pragma unroll
        for (int rep = 0; rep < 4; ++rep) {
            const int c2 = rep * 8 + cq;
            const int c  = 2 * c2;
            float va = 0.f, vb = 0.f;
#pragma unroll
            for (int d = 0; d < NODE_DIM; ++d) {
                const float nd = sN[jl][d];
                va += nd * sE1[NODE_DIM + d][c];
                vb += nd * sE1[NODE_DIM + d][c + 1];
            }
            h2 vv = { (_Float16)va, (_Float16)vb };
            VH[((size_t)(b * MAX_NODES + i0 + jl) << 5) + c2] = h2_to_u32(vv);
        }
    }
}

// ---------------------------------------------------------------------------
// Kernel 2: edge probabilities + adjacency.  (R4 geometry, f16 math, 8 w/SIMD)
// Block = 256 thr (4 waves), tile 64 i x 32 j. Lane owns i; wave w owns 8 j.
// uA = 32 VGPR of f16x2; V tile (4KB) in LDS read b128 broadcast; E2 f16x2
// in SGPRs. rcp-based sigmoid. LDS 12.3KB, VGPR target <64 -> 8 waves/SIMD.
// 72 tiles/batch (jt >= 2*bi); partial iff (jt>>1)==bi.
// ---------------------------------------------------------------------------
__global__ __launch_bounds__(256, 8) void edge_gen(
    const unsigned int* __restrict__ UPKH, const unsigned int* __restrict__ VH,
    const float* __restrict__ E2,  const float* __restrict__ eb2,
    float* __restrict__ adj)
{
    const int b = blockIdx.y;
    // decode tile: bi in 0..7 (64-wide i), jt in 2*bi..15 (32-wide j)
    int t = blockIdx.x, bi = 0;
    while (t >= 16 - 2 * bi) { t -= 16 - 2 * bi; ++bi; }
    const int jt = 2 * bi + t;
    const bool partial = (jt >> 1) == bi;    // j-window inside i-block

    const int tid  = threadIdx.x;
    const int lane = tid & 63;
    const int wv   = tid >> 6;               // 0..3
    const int i0 = bi * 64, j0 = jt * 32;
    const int i  = i0 + lane;

    __shared__ unsigned int sV[32 * 32];     // 32 rows x 64ch f16 = 4 KB
    __shared__ float P[32][65];              // tile probs for mirror (8.3 KB)

    // stage V tile: 4 KB contiguous, 1 float4 per thread
    {
        const float4* src = (const float4*)(VH + ((size_t)(b * MAX_NODES + j0) << 5));
        ((float4*)sV)[tid] = src[tid];
    }

    // U row for this lane: 32 f16x2 dwords, coalesced per c2
    unsigned int uA[32];
#pragma unroll
    for (int c2 = 0; c2 < 32; ++c2)
        uA[c2] = UPKH[((size_t)b * 32 + c2) * MAX_NODES + i];

    // E2 -> packed f16x2 in SGPRs
    unsigned int wb[32];
#pragma unroll
    for (int c2 = 0; c2 < 32; ++c2) {
        h2 w = { (_Float16)E2[2 * c2], (_Float16)E2[2 * c2 + 1] };
        wb[c2] = __builtin_amdgcn_readfirstlane(h2_to_u32(w));
    }

    const float bias = eb2[0];
    float* adjb = adj + (size_t)b * MAX_NODES * MAX_NODES;
    const h2 zh = { (_Float16)0.f, (_Float16)0.f };
    __syncthreads();

#pragma unroll 1
    for (int jj = 0; jj < 8; ++jj) {
        const int jl = wv * 8 + jj;          // 0..31
        const int j  = j0 + jl;
        const float4* vrow = (const float4*)&sV[jl * 32];

        float a0 = 0.f, a1 = 0.f;
#pragma unroll
        for (int q = 0; q < 8; ++q) {
            union { float4 f4; unsigned int u[4]; } vv;
            vv.f4 = vrow[q];                 // ds_read_b128, uniform
#pragma unroll
            for (int k = 0; k < 4; ++k) {
                const int c2 = 4 * q + k;
                const h2 v = u32_to_h2(vv.u[k]);
                const h2 w = u32_to_h2(wb[c2]);
                h2 s = u32_to_h2(uA[c2]) + v;
                s = __builtin_elementwise_max(s, zh);
                if (k & 1) a1 = FDOT2(s, w, a1);
                else       a0 = FDOT2(s, w, a0);
            }
        }
        const float x = a0 + a1 + bias;
        const float p = __builtin_amdgcn_rcpf(1.0f + __expf(-x));

        if (!partial) {
            adjb[(size_t)j * MAX_NODES + i] = p;     // lower half, coalesced
            P[jl][lane] = p;                         // stage for mirror
        } else {
            if (i < j)       { adjb[(size_t)j * MAX_NODES + i] = p;
                               adjb[(size_t)i * MAX_NODES + j] = p; }
            else if (i == j)   adjb[(size_t)j * MAX_NODES + i] = 0.0f;
        }
    }

    if (!partial) {
        __syncthreads();
        // mirror: adj[i0+r][j0..j0+31]; thread owns row r = tid&63, quarter q
        const int r = tid & 63;
        const int q = tid >> 6;              // 0..3
        const size_t rowbase = (size_t)(i0 + r) * MAX_NODES + j0 + q * 8;
        float4 o0, o1;
        o0.x = P[q * 8 + 0][r]; o0.y = P[q * 8 + 1][r];
        o0.z = P[q * 8 + 2][r]; o0.w = P[q * 8 + 3][r];
        o1.x = P[q * 8 + 4][r]; o1.y = P[q * 8 + 5][r];
        o1.z = P[q * 8 + 6][r]; o1.w = P[q * 8 + 7][r];
        *(float4*)&adjb[rowbase]     = o0;
        *(float4*)&adjb[rowbase + 4] = o1;
    }
}

// ---------------------------------------------------------------------------
extern "C" void kernel_launch(void* const* d_in, const int* in_sizes, int n_in,
                              void* d_out, int out_size, void* d_ws, size_t ws_size,
                              hipStream_t stream)
{
    const float* z   = (const float*)d_in[0];
    const float* W1  = (const float*)d_in[1];
    const float* b1  = (const float*)d_in[2];
    const float* W2  = (const float*)d_in[3];
    const float* b2  = (const float*)d_in[4];
    const float* E1  = (const float*)d_in[5];
    const float* eb1 = (const float*)d_in[6];
    const float* E2  = (const float*)d_in[7];
    const float* eb2 = (const float*)d_in[8];

    float* nodes_out = (float*)d_out;                                   // [32,512,8]
    float* adj       = (float*)d_out + BATCH * MAX_NODES * NODE_DIM;    // [32,512,512]

    unsigned int* UPKH = (unsigned int*)d_ws;       // 2 MB
    unsigned int* VHp  = UPKH + UPKH_DWORDS;        // 2 MB

    dim3 g1(BATCH, 16);
    gen_nodes_uv<<<g1, 256, 0, stream>>>(z, W1, b1, W2, b2, E1, eb1,
                                         nodes_out, UPKH, VHp);

    dim3 g2(72, BATCH);
    edge_gen<<<g2, 256, 0, stream>>>(UPKH, VHp, E2, eb2, adj);
}